// Round 1
// baseline (204.911 us; speedup 1.0000x reference)
//
#include <hip/hip_runtime.h>
#include <cstdint>
#include <cstddef>

#define N_IMG 32
#define C_IN 192
#define HW 56
#define SPAT (HW*HW)       // 3136
#define C_OUT 384
#define HP 58              // padded H/W
#define KPOS 9

#define BM 128
#define BN 128
#define BK 64
#define NTILE_S 25         // ceil(3136/128)
#define NTILE_CO 3
#define GRID_MAIN (N_IMG*NTILE_CO*NTILE_S)  // 2400

typedef __attribute__((ext_vector_type(8))) short short8;
typedef __attribute__((ext_vector_type(4))) float f32x4;

__device__ __forceinline__ unsigned short f2bf(float f) {
  union { float f; unsigned u; } v; v.f = f;
  unsigned u = v.u;
  unsigned r = (u + 0x7FFFu + ((u >> 16) & 1u)) >> 16;
  return (unsigned short)r;
}

__device__ __forceinline__ void async_load16(const void* gsrc, void* ldst) {
  __builtin_amdgcn_global_load_lds(
      (const __attribute__((address_space(1))) unsigned int*)gsrc,
      (__attribute__((address_space(3))) unsigned int*)ldst,
      16, 0, 0);
}

// ---- prep: W (Cout,C,3,3) f32 -> Wp[co][pos][c] bf16 ----
__global__ void pack_w(const float* __restrict__ W, unsigned short* __restrict__ Wp) {
  int idx = blockIdx.x*256 + threadIdx.x;
  if (idx >= C_OUT*KPOS*C_IN) return;
  int c   = idx % C_IN;
  int pos = (idx / C_IN) % KPOS;
  int co  = idx / (C_IN*KPOS);
  float v = W[((size_t)co*C_IN + c)*KPOS + pos];
  Wp[idx] = f2bf(v);
}

// ---- prep: zero the pad border of Xp[n][58][58][192] ----
__global__ void zero_border(unsigned short* __restrict__ Xp) {
  int idx = blockIdx.x*256 + threadIdx.x;
  if (idx >= N_IMG*228*C_IN) return;
  int c    = idx % C_IN;
  int cell = (idx / C_IN) % 228;
  int n    = idx / (C_IN*228);
  int hh, ww;
  if (cell < 116) { hh = (cell < 58) ? 0 : 57; ww = cell % 58; }
  else { int b2 = cell - 116; ww = (b2 < 56) ? 0 : 57; hh = 1 + (b2 % 56); }
  Xp[(((size_t)n*HP + hh)*HP + ww)*C_IN + c] = 0;
}

// ---- prep: x NCHW f32 -> Xp padded NHWC bf16 (interior) ----
__global__ void pack_x(const float* __restrict__ x, unsigned short* __restrict__ Xp) {
  __shared__ float tile[64*57];
  int b  = blockIdx.x;
  int cb = b % 3;
  int h  = (b/3) % HW;
  int n  = b / (3*HW);
  int tid = threadIdx.x;
  const float* src = x + (size_t)n*C_IN*SPAT + (size_t)cb*64*SPAT + h*HW;
  #pragma unroll
  for (int i = 0; i < 14; ++i) {           // 64c * 56w = 3584 = 14*256
    int idx = i*256 + tid;
    int c = idx / HW, w = idx % HW;
    tile[c*57 + w] = src[(size_t)c*SPAT + w];
  }
  __syncthreads();
  unsigned short* dst = Xp + (((size_t)n*HP + h + 1)*HP + 1)*C_IN + cb*64;
  #pragma unroll
  for (int i = 0; i < 14; ++i) {
    int idx = i*256 + tid;
    int w = idx / 64, c = idx % 64;
    dst[(size_t)w*C_IN + c] = f2bf(tile[c*57 + w]);
  }
}

// ---- main: implicit-GEMM conv, 128x128 tile, bf16 MFMA ----
__global__ __launch_bounds__(256) void conv_gemm(
    const unsigned short* __restrict__ Wp,
    const unsigned short* __restrict__ Xp,
    const float* __restrict__ bias,
    float* __restrict__ out)
{
  __shared__ __attribute__((aligned(16))) unsigned short As[BM*BK];  // 16 KB
  __shared__ __attribute__((aligned(16))) unsigned short Bs[BN*BK];  // 16 KB

  int bid = blockIdx.x;
  int logical = (bid & 7) * (GRID_MAIN/8) + (bid >> 3);   // XCD-bijective (2400%8==0)
  int cotile = logical % NTILE_CO;
  int rest   = logical / NTILE_CO;
  int stile  = rest % NTILE_S;
  int n      = rest / NTILE_S;

  const int tid  = threadIdx.x;
  const int lane = tid & 63;
  const int wv   = tid >> 6;
  const int l7   = lane & 7;
  const int l3   = lane >> 3;
  const int lanep = lane & 15;
  const int laneq = lane >> 4;
  const int gsl  = ((l7 ^ l3) << 3);   // pre-swizzled c-offset of this lane's 16B slot

  // staging bases: 4 chunks/wave, 8 rows/chunk, row = chunk*8 + l3
  size_t aBase[4];
  size_t bBase[4];
  #pragma unroll
  for (int i = 0; i < 4; ++i) {
    int r  = (wv*4 + i)*8 + l3;
    int co = cotile*BM + r;
    aBase[i] = ((size_t)co*KPOS)*C_IN + gsl;
    int sg = stile*BN + r;
    if (sg > SPAT-1) sg = SPAT-1;      // tail clamp (stores masked later)
    int hh = sg / HW, ww = sg % HW;
    bBase[i] = (((size_t)n*HP + hh)*HP + ww)*C_IN + gsl;
  }

  // fragment read offsets (bf16 elements); slot = (kk*4+laneq) ^ l7, kk=1 is XOR 32
  const int aoff0 = (((wv>>1)*64 + lanep) << 6) + ((laneq ^ l7) << 3);
  const int boff0 = (((wv&1)*64 + lanep) << 6) + ((laneq ^ l7) << 3);

  f32x4 acc[4][4];
  #pragma unroll
  for (int mf = 0; mf < 4; ++mf)
    #pragma unroll
    for (int nf = 0; nf < 4; ++nf)
      acc[mf][nf] = (f32x4){0.f, 0.f, 0.f, 0.f};

  for (int pos = 0; pos < KPOS; ++pos) {
    const int kh = pos / 3, kw = pos % 3;
    const size_t posOff = ((size_t)kh*HP + kw)*C_IN;
    for (int c0 = 0; c0 < C_IN; c0 += BK) {
      __syncthreads();                 // previous tile's reads done
      #pragma unroll
      for (int i = 0; i < 4; ++i) {
        async_load16(Wp + aBase[i] + pos*C_IN + c0, &As[(wv*4 + i)*512]);
        async_load16(Xp + bBase[i] + posOff   + c0, &Bs[(wv*4 + i)*512]);
      }
      __syncthreads();                 // compiler drains vmcnt(0) before barrier
      #pragma unroll
      for (int kk = 0; kk < 2; ++kk) {
        const int kx = kk << 5;
        short8 av[4], bv[4];
        #pragma unroll
        for (int mf = 0; mf < 4; ++mf)
          av[mf] = *(const short8*)&As[(aoff0 + mf*1024) ^ kx];
        #pragma unroll
        for (int nf = 0; nf < 4; ++nf)
          bv[nf] = *(const short8*)&Bs[(boff0 + nf*1024) ^ kx];
        #pragma unroll
        for (int mf = 0; mf < 4; ++mf)
          #pragma unroll
          for (int nf = 0; nf < 4; ++nf)
            acc[mf][nf] = __builtin_amdgcn_mfma_f32_16x16x32_bf16(
                av[mf], bv[nf], acc[mf][nf], 0, 0, 0);
      }
    }
  }

  // epilogue: D col = lane&15 (spatial), row = laneq*4+i (Cout)  [m89-verified]
  const int coB = cotile*BM + (wv>>1)*64;
  const int sB  = stile*BN + (wv&1)*64;
  #pragma unroll
  for (int mf = 0; mf < 4; ++mf) {
    #pragma unroll
    for (int i = 0; i < 4; ++i) {
      int co = coB + mf*16 + laneq*4 + i;
      float bi = bias[co];
      float* orow = out + ((size_t)n*C_OUT + co)*SPAT;
      #pragma unroll
      for (int nf = 0; nf < 4; ++nf) {
        int s = sB + nf*16 + lanep;
        if (s < SPAT) orow[s] = acc[mf][nf][i] + bi;
      }
    }
  }
}

// ---- fallback: direct fp32 conv (used only if ws too small) ----
__global__ void conv_naive(const float* __restrict__ x, const float* __restrict__ W,
                           const float* __restrict__ bias, float* __restrict__ out) {
  size_t idx = (size_t)blockIdx.x*256 + threadIdx.x;
  if (idx >= (size_t)N_IMG*C_OUT*SPAT) return;
  int s  = idx % SPAT;
  int co = (int)((idx / SPAT) % C_OUT);
  int n  = (int)(idx / ((size_t)SPAT*C_OUT));
  int h = s / HW, w = s % HW;
  float acc = bias[co];
  for (int c = 0; c < C_IN; ++c) {
    for (int kh = 0; kh < 3; ++kh) {
      int hh = h + kh - 1;
      if (hh < 0 || hh >= HW) continue;
      for (int kw = 0; kw < 3; ++kw) {
        int ww = w + kw - 1;
        if (ww < 0 || ww >= HW) continue;
        acc += x[(((size_t)n*C_IN + c)*HW + hh)*HW + ww]
             * W[(((size_t)co*C_IN + c)*3 + kh)*3 + kw];
      }
    }
  }
  out[idx] = acc;
}

extern "C" void kernel_launch(void* const* d_in, const int* in_sizes, int n_in,
                              void* d_out, int out_size, void* d_ws, size_t ws_size,
                              hipStream_t stream) {
  const float* x = (const float*)d_in[0];
  const float* W = (const float*)d_in[1];
  const float* b = (const float*)d_in[2];
  float* out = (float*)d_out;

  const size_t WP_ELEMS = (size_t)C_OUT*KPOS*C_IN;        // 663,552
  const size_t XP_ELEMS = (size_t)N_IMG*HP*HP*C_IN;       // 20,668,416
  const size_t NEED = (WP_ELEMS + XP_ELEMS)*2;            // ~40.7 MB

  if (ws_size >= NEED) {
    unsigned short* Wp = (unsigned short*)d_ws;
    unsigned short* Xp = Wp + WP_ELEMS;                   // 16B-aligned (1,327,104 B)
    zero_border<<<(N_IMG*228*C_IN + 255)/256, 256, 0, stream>>>(Xp);
    pack_w<<<(int)((WP_ELEMS + 255)/256), 256, 0, stream>>>(W, Wp);
    pack_x<<<N_IMG*HW*3, 256, 0, stream>>>(x, Xp);
    conv_gemm<<<GRID_MAIN, 256, 0, stream>>>(Wp, Xp, b, out);
  } else {
    size_t total = (size_t)N_IMG*C_OUT*SPAT;
    conv_naive<<<(int)((total + 255)/256), 256, 0, stream>>>(x, W, b, out);
  }
}

// Round 2
// 186.425 us; speedup vs baseline: 1.0992x; 1.0992x over previous
//
#include <hip/hip_runtime.h>
#include <cstdint>
#include <cstddef>

#define N_IMG 32
#define C_IN 192
#define HW 56
#define SPAT 3136
#define C_OUT 384
#define HP 58
#define KPOS 9
#define KTOT 1728          // 9*192
#define NSUB 54            // KTOT/32

#define BM 128             // Cout per block
#define BN 256             // spatial-flat per block
#define NT_CO 3
#define NT_S  392          // 100352/256 exact
#define GRID_MAIN (NT_CO*NT_S)   // 1176, /8 = 147 exact

typedef __attribute__((ext_vector_type(8))) short short8;
typedef __attribute__((ext_vector_type(4))) float f32x4;

__device__ __forceinline__ unsigned short f2bf(float f) {
  union { float f; unsigned u; } v; v.f = f;
  unsigned u = v.u;
  unsigned r = (u + 0x7FFFu + ((u >> 16) & 1u)) >> 16;
  return (unsigned short)r;
}

__device__ __forceinline__ void async_load16(const void* gsrc, void* ldst) {
  __builtin_amdgcn_global_load_lds(
      (const __attribute__((address_space(1))) unsigned int*)gsrc,
      (__attribute__((address_space(3))) unsigned int*)ldst,
      16, 0, 0);
}

// ---- prep: W (Cout,C,3,3) f32 -> Wp[co][pos][c] bf16 (K linear = pos*192+c) ----
__global__ void pack_w(const float* __restrict__ W, unsigned short* __restrict__ Wp) {
  int idx = blockIdx.x*256 + threadIdx.x;
  if (idx >= C_OUT*KPOS*C_IN) return;
  int c   = idx % C_IN;
  int pos = (idx / C_IN) % KPOS;
  int co  = idx / (C_IN*KPOS);
  float v = W[((size_t)co*C_IN + c)*KPOS + pos];
  Wp[idx] = f2bf(v);
}

// ---- prep: zero pad border of Xp[n][58][58][192] ----
__global__ void zero_border(unsigned short* __restrict__ Xp) {
  int idx = blockIdx.x*256 + threadIdx.x;
  if (idx >= N_IMG*228*C_IN) return;
  int c    = idx % C_IN;
  int cell = (idx / C_IN) % 228;
  int n    = idx / (C_IN*228);
  int hh, ww;
  if (cell < 116) { hh = (cell < 58) ? 0 : 57; ww = cell % 58; }
  else { int b2 = cell - 116; ww = (b2 < 56) ? 0 : 57; hh = 1 + (b2 % 56); }
  Xp[(((size_t)n*HP + hh)*HP + ww)*C_IN + c] = 0;
}

// ---- prep: x NCHW f32 -> Xp padded NHWC bf16 (interior) ----
__global__ void pack_x(const float* __restrict__ x, unsigned short* __restrict__ Xp) {
  __shared__ float tile[64*57];
  int b  = blockIdx.x;
  int cb = b % 3;
  int h  = (b/3) % HW;
  int n  = b / (3*HW);
  int tid = threadIdx.x;
  const float* src = x + (size_t)n*C_IN*SPAT + (size_t)cb*64*SPAT + h*HW;
  #pragma unroll
  for (int i = 0; i < 14; ++i) {
    int idx = i*256 + tid;
    int c = idx / HW, w = idx % HW;
    tile[c*57 + w] = src[(size_t)c*SPAT + w];
  }
  __syncthreads();
  unsigned short* dst = Xp + (((size_t)n*HP + h + 1)*HP + 1)*C_IN + cb*64;
  #pragma unroll
  for (int i = 0; i < 14; ++i) {
    int idx = i*256 + tid;
    int w = idx / 64, c = idx % 64;
    dst[(size_t)w*C_IN + c] = f2bf(tile[c*57 + w]);
  }
}

// ---- main: implicit-GEMM conv, 128x256 tile, 8 waves, counted-vmcnt ring-4 pipeline ----
__global__ __launch_bounds__(512, 2) void conv_gemm(
    const unsigned short* __restrict__ Wp,
    const unsigned short* __restrict__ Xp,
    const float* __restrict__ bias,
    float* __restrict__ out)
{
  // ring of 4 sub-buffers: A[128][32] (4096 shorts) + B[256][32] (8192 shorts) = 24KB each
  __shared__ __attribute__((aligned(16))) unsigned short lds[4][12288];

  int bid = blockIdx.x;
  int wg = (bid & 7) * (GRID_MAIN/8) + (bid >> 3);   // XCD-bijective (1176%8==0)
  int cotile = wg % NT_CO;
  int stile  = wg / NT_CO;

  const int tid   = threadIdx.x;
  const int lane  = tid & 63;
  const int wv    = tid >> 6;       // 0..7
  const int wm    = wv >> 2;        // 0..1  (M position)
  const int wn    = wv & 3;         // 0..3  (N position)
  const int lanep = lane & 15;
  const int laneq = lane >> 4;
  const int l2    = lane >> 2;      // row within a 16-row staging chunk
  const int l4    = lane & 3;       // 16B slot within a 64B row
  const int chunkSw = l4 ^ (l2 & 3);   // pre-swizzled source chunk

  // ---- staging source pointers (per-lane) ----
  // A: wave wv stages A-rows wv*16 + l2 (1 instr/wave/sub)
  const int aRow = cotile*BM + wv*16 + l2;
  const unsigned short* aSrc = Wp + (size_t)aRow*KTOT + chunkSw*8;

  // B: wave wv, instr i stages B-rows (wv*2+i)*16 + l2 (2 instr/wave/sub)
  const unsigned short* bSrc0;
  const unsigned short* bSrc1;
  {
    int r0 = (wv*2 + 0)*16 + l2;
    int f0 = stile*BN + r0;
    int n0 = f0 / SPAT, sp0 = f0 % SPAT;
    bSrc0 = Xp + (((size_t)n0*HP + sp0/HW)*HP + sp0%HW)*C_IN + chunkSw*8;
    int r1 = (wv*2 + 1)*16 + l2;
    int f1 = stile*BN + r1;
    int n1 = f1 / SPAT, sp1 = f1 % SPAT;
    bSrc1 = Xp + (((size_t)n1*HP + sp1/HW)*HP + sp1%HW)*C_IN + chunkSw*8;
  }

  // LDS staging dests (wave-uniform within slot 0; add slot*12288)
  unsigned short* aDst  = &lds[0][wv*512];
  unsigned short* bDst0 = &lds[0][4096 + (wv*2 + 0)*512];
  unsigned short* bDst1 = &lds[0][4096 + (wv*2 + 1)*512];

  // ds_read element bases within a slot (add mf*512 / nf*512, + slot*12288)
  const int swz8   = (laneq ^ (lanep & 3)) << 3;
  const int aRdBase = (wm*64 + lanep)*32 + swz8;
  const int bRdBase = 4096 + (wn*64 + lanep)*32 + swz8;

  f32x4 acc[4][4];
  #pragma unroll
  for (int mf = 0; mf < 4; ++mf)
    #pragma unroll
    for (int nf = 0; nf < 4; ++nf)
      acc[mf][nf] = (f32x4){0.f, 0.f, 0.f, 0.f};

  // K sub-tile t -> B image offset: pos = t/6 (kh=pos/3, kw=pos%3), c0 = (t%6)*32
  auto bOffOf = [](int t) {
    int kh = t / 18;
    int r  = t - kh*18;
    int kw = r / 6;
    int c6 = r - kw*6;
    return (kh*HP + kw)*C_IN + c6*32;
  };

  auto stage = [&](int t) {
    int slot = t & 3;
    async_load16(aSrc + t*32, aDst + slot*12288);
    int bo = bOffOf(t);
    async_load16(bSrc0 + bo, bDst0 + slot*12288);
    async_load16(bSrc1 + bo, bDst1 + slot*12288);
  };

#define PHASE(sv, VMC, DO_STAGE)                                            \
  {                                                                         \
    asm volatile("s_waitcnt vmcnt(" #VMC ")" ::: "memory");                 \
    __builtin_amdgcn_s_barrier();                                           \
    __builtin_amdgcn_sched_barrier(0);                                      \
    const int slot_ = (sv) & 3;                                             \
    const unsigned short* la_ = &lds[slot_][0];                             \
    short8 av_[4], bv_[4];                                                  \
    _Pragma("unroll")                                                       \
    for (int mf = 0; mf < 4; ++mf)                                          \
      av_[mf] = *(const short8*)&la_[aRdBase + mf*512];                     \
    _Pragma("unroll")                                                       \
    for (int nf = 0; nf < 4; ++nf)                                          \
      bv_[nf] = *(const short8*)&la_[bRdBase + nf*512];                     \
    if (DO_STAGE) stage((sv) + 3);                                          \
    __builtin_amdgcn_s_setprio(1);                                          \
    _Pragma("unroll")                                                       \
    for (int mf = 0; mf < 4; ++mf)                                          \
      _Pragma("unroll")                                                     \
      for (int nf = 0; nf < 4; ++nf)                                        \
        acc[mf][nf] = __builtin_amdgcn_mfma_f32_16x16x32_bf16(              \
            av_[mf], bv_[nf], acc[mf][nf], 0, 0, 0);                        \
    __builtin_amdgcn_s_setprio(0);                                          \
    __builtin_amdgcn_sched_barrier(0);                                      \
  }

  // prologue: stage subs 0,1,2 (9 loads/wave in flight)
  stage(0); stage(1); stage(2);

  // main loop: 2-sub-deep counted vmcnt (3 loads/wave/sub -> vmcnt(6))
  for (int s = 0; s < 51; ++s)
    PHASE(s, 6, true);
  // epilogue: drain 6 -> 3 -> 0
  PHASE(51, 6, false);
  PHASE(52, 3, false);
  PHASE(53, 0, false);
#undef PHASE

  // ---- epilogue: D col = lane&15 -> spatial, row = laneq*4+i -> Cout ----
  const int coB = cotile*BM + wm*64;
  const int fB  = stile*BN + wn*64;
  #pragma unroll
  for (int nf = 0; nf < 4; ++nf) {
    int f  = fB + nf*16 + lanep;
    int n  = f / SPAT;
    int sp = f % SPAT;
    float* obase = out + (size_t)n*C_OUT*SPAT + sp;
    #pragma unroll
    for (int mf = 0; mf < 4; ++mf) {
      #pragma unroll
      for (int i = 0; i < 4; ++i) {
        int co = coB + mf*16 + laneq*4 + i;
        obase[(size_t)co*SPAT] = acc[mf][nf][i] + bias[co];
      }
    }
  }
}

// ---- fallback: direct fp32 conv (used only if ws too small) ----
__global__ void conv_naive(const float* __restrict__ x, const float* __restrict__ W,
                           const float* __restrict__ bias, float* __restrict__ out) {
  size_t idx = (size_t)blockIdx.x*256 + threadIdx.x;
  if (idx >= (size_t)N_IMG*C_OUT*SPAT) return;
  int s  = idx % SPAT;
  int co = (int)((idx / SPAT) % C_OUT);
  int n  = (int)(idx / ((size_t)SPAT*C_OUT));
  int h = s / HW, w = s % HW;
  float acc = bias[co];
  for (int c = 0; c < C_IN; ++c)
    for (int kh = 0; kh < 3; ++kh) {
      int hh = h + kh - 1;
      if (hh < 0 || hh >= HW) continue;
      for (int kw = 0; kw < 3; ++kw) {
        int ww = w + kw - 1;
        if (ww < 0 || ww >= HW) continue;
        acc += x[(((size_t)n*C_IN + c)*HW + hh)*HW + ww]
             * W[(((size_t)co*C_IN + c)*3 + kh)*3 + kw];
      }
    }
  out[idx] = acc;
}

extern "C" void kernel_launch(void* const* d_in, const int* in_sizes, int n_in,
                              void* d_out, int out_size, void* d_ws, size_t ws_size,
                              hipStream_t stream) {
  const float* x = (const float*)d_in[0];
  const float* W = (const float*)d_in[1];
  const float* b = (const float*)d_in[2];
  float* out = (float*)d_out;

  const size_t WP_ELEMS = (size_t)C_OUT*KPOS*C_IN;        // 663,552
  const size_t XP_ELEMS = (size_t)N_IMG*HP*HP*C_IN;       // 20,668,416
  const size_t NEED = (WP_ELEMS + XP_ELEMS)*2;            // ~40.7 MB

  if (ws_size >= NEED) {
    unsigned short* Wp = (unsigned short*)d_ws;
    unsigned short* Xp = Wp + WP_ELEMS;                   // 16B-aligned
    zero_border<<<(N_IMG*228*C_IN + 255)/256, 256, 0, stream>>>(Xp);
    pack_w<<<(int)((WP_ELEMS + 255)/256), 256, 0, stream>>>(W, Wp);
    pack_x<<<N_IMG*HW*3, 256, 0, stream>>>(x, Xp);
    conv_gemm<<<GRID_MAIN, 512, 0, stream>>>(Wp, Xp, b, out);
  } else {
    size_t total = (size_t)N_IMG*C_OUT*SPAT;
    conv_naive<<<(int)((total + 255)/256), 256, 0, stream>>>(x, W, b, out);
  }
}